// Round 6
// baseline (168.242 us; speedup 1.0000x reference)
//
#include <hip/hip_runtime.h>
#include <math.h>

// Problem constants
#define NIMG 512          // B*C = 64*8
#define HH   256          // H
#define MM   32           // M (kept modes per axis)
#define EPSF 1e-8f
#define PAD2 18           // padded k1-stride (float2 units) for T2

// d_out float offsets (outputs concatenated flat in reference return order)
#define O0 0u             // modal_energies        [512][32][32]
#define O1 524288u        // modal_uncertainties   [512][32][32]
#define O2 1048576u       // energy_fractions      [512][32][32]
#define O3 1572864u       // weighted_importance   [512][32][32]
#define O4 2097152u       // uncertainty_spectrum  [32][32]
#define O5 2098176u       // energy_spectrum       [32][32]
#define O6 2099200u       // modal_errors          [512][32][32]
#define O7 2623488u       // calibration_scores    [32][32]

// d_ws float offsets
#define PM_OFF  512                          // pred modes [512][32][32][2]
#define GM_OFF  (512 + NIMG*MM*MM*2)         // gt modes
#define TOT_OFF (512 + 2*NIMG*MM*MM*2)       // per-image total energy [512]

// ---------------------------------------------------------------------------
// Truncated 2D DFT: one block per (image, tensor). 512 threads.
// Thread t = (col = t&255, half = t>>8). Stage 1 (DIT-8 over n1 = a + 32b):
//   per a, constant-twiddle 8-pt real DFT over b, then for the thread's two
//   m-values (m = 2*half, 2*half+1): X[8m+r] += M_m(a) * (T_r(a) * Z[r]).
//   16 k1 per thread -> 32 NAMED scalar accumulators (no arrays, no runtime
//   indices -> no scratch; rounds 4/5 lesson). All twiddles by in-register
//   complex recurrence; input loads 2-deep prefetched.
// Stage 2 (two passes over k1-halves): threads with half==p flush their 16
//   k1 to LDS; all 512 threads then compute 1 mode each per pass (radix-4
//   fold over n2, residue k2%4 wave-uniform, rotator recurrence).
__global__ __launch_bounds__(512, 4) void dft_kernel(
    const float* __restrict__ pred, const float* __restrict__ gt,
    float* __restrict__ Pm, float* __restrict__ Gm,
    float* __restrict__ tot, float* __restrict__ out_energy)
{
  __shared__ __align__(16) float2 T2[256 * PAD2];   // 36864 B
  __shared__ float red[8];

  const int t    = threadIdx.x;
  const int col  = t & 255;          // n2
  const int half = t >> 8;           // 0: k1 0..15, 1: k1 16..31
  const int img  = blockIdx.x & (NIMG - 1);
  const int isGt = blockIdx.x >> 9;
  const float* __restrict__ x =
      (isGt ? gt : pred) + (size_t)img * (HH * HH) + col;

  // ---- stage 1 ----
  float aR0=0.f,aI0=0.f,aR1=0.f,aI1=0.f,aR2=0.f,aI2=0.f,aR3=0.f,aI3=0.f;
  float aR4=0.f,aI4=0.f,aR5=0.f,aI5=0.f,aR6=0.f,aI6=0.f,aR7=0.f,aI7=0.f;
  float aR8=0.f,aI8=0.f,aR9=0.f,aI9=0.f,aR10=0.f,aI10=0.f,aR11=0.f,aI11=0.f;
  float aR12=0.f,aI12=0.f,aR13=0.f,aI13=0.f,aR14=0.f,aI14=0.f,aR15=0.f,aI15=0.f;

  // residue chains T_r(a) = e^{-2pi i r a/256}, r = 1..7
  float c1r=1.f,c1i=0.f,c2r=1.f,c2i=0.f,c3r=1.f,c3i=0.f,c4r=1.f,c4i=0.f;
  float c5r=1.f,c5i=0.f,c6r=1.f,c6i=0.f,c7r=1.f,c7i=0.f;
  // m-chains M_m(a) = e^{-2pi i m a/32}; this thread's m = 2*half, 2*half+1
  float mAr=1.f, mAi=0.f, mBr=1.f, mBi=0.f;
  const float fAx = half ? 0.92387953f : 1.0f;           // W32^2 : W32^0
  const float fAy = half ? -0.38268343f : 0.0f;
  const float fBx = half ? 0.83146961f : 0.98078528f;    // W32^3 : W32^1
  const float fBy = half ? -0.55557023f : -0.19509032f;

  // step multipliers e^{-2pi i r/256}: compile-time literals
  const float e1x = 0.99969882f,  e1y = -0.02454123f;
  const float e2x = 0.99879546f,  e2y = -0.04906767f;
  const float e3x = 0.99729046f,  e3y = -0.07356456f;
  const float e4x = 0.99518473f,  e4y = -0.09801714f;
  const float e5x = 0.99247953f,  e5y = -0.12241067f;
  const float e6x = 0.98917651f,  e6y = -0.14673047f;
  const float e7x = 0.98527764f,  e7y = -0.17096184f;

#define ACC2N(Ra, Ia, Rb, Ib, Yr, Yi)                                     \
    Ra = fmaf(mAr,(Yr), fmaf(-mAi,(Yi), Ra));                             \
    Ia = fmaf(mAr,(Yi), fmaf( mAi,(Yr), Ia));                             \
    Rb = fmaf(mBr,(Yr), fmaf(-mBi,(Yi), Rb));                             \
    Ib = fmaf(mBr,(Yi), fmaf( mBi,(Yr), Ib));

#define CPLX2(cr, ci, Zr, Zi, Ra, Ia, Rb, Ib)                             \
    { float Yr_ = fmaf(cr,(Zr), -((ci)*(Zi)));                            \
      float Yi_ = fmaf(cr,(Zi),  (ci)*(Zr));                              \
      ACC2N(Ra, Ia, Rb, Ib, Yr_, Yi_) }

#define ROT(cr, ci, ex, ey)                                               \
    { float nr_ = fmaf(cr, ex, -((ci)*(ey)));                             \
      float ni_ = fmaf(cr, ey,  (ci)*(ex));                               \
      cr = nr_; ci = ni_; }

#define LOADV(V, aa)                                                      \
    V[0] = x[(aa)*256];         V[1] = x[(aa)*256 +  8192];               \
    V[2] = x[(aa)*256 + 16384]; V[3] = x[(aa)*256 + 24576];               \
    V[4] = x[(aa)*256 + 32768]; V[5] = x[(aa)*256 + 40960];               \
    V[6] = x[(aa)*256 + 49152]; V[7] = x[(aa)*256 + 57344];

#define BODY(V)                                                           \
  {                                                                       \
    float v0=V[0],v1=V[1],v2=V[2],v3=V[3],v4=V[4],v5=V[5],v6=V[6],v7=V[7];\
    float w0=v0+v4, w1=v1+v5, w2=v2+v6, w3=v3+v7;                         \
    float d0=v0-v4, d1=v1-v5, d2=v2-v6, d3=v3-v7;                         \
    float A0=w0+w2, A1=w0-w2, A2=w1+w3, A3=w1-w3;                         \
    float Z0=A0+A2, Z4=A0-A2;                                             \
    float Z2r=A1, Z2i=-A3;                                                \
    const float SQ = 0.70710678f;                                         \
    float pp=SQ*(d1-d3), qq2=SQ*(d1+d3);                                  \
    float Z1r=d0+pp, Z1i=-(d2+qq2);                                       \
    float Z3r=d0-pp, Z3i=d2-qq2;                                          \
    /* r=0: Y = (Z0, 0) */                                                \
    aR0 = fmaf(mAr,Z0,aR0); aI0 = fmaf(mAi,Z0,aI0);                       \
    aR8 = fmaf(mBr,Z0,aR8); aI8 = fmaf(mBi,Z0,aI8);                       \
    /* r=4: Y = T_4 * Z4 (Z4 real) */                                     \
    { float Yr_=c4r*Z4, Yi_=c4i*Z4; ACC2N(aR4,aI4,aR12,aI12,Yr_,Yi_) }    \
    CPLX2(c1r,c1i,Z1r, Z1i, aR1,aI1,aR9,aI9)                              \
    CPLX2(c2r,c2i,Z2r, Z2i, aR2,aI2,aR10,aI10)                            \
    CPLX2(c3r,c3i,Z3r, Z3i, aR3,aI3,aR11,aI11)                            \
    CPLX2(c5r,c5i,Z3r,-Z3i, aR5,aI5,aR13,aI13)                            \
    CPLX2(c6r,c6i,Z2r,-Z2i, aR6,aI6,aR14,aI14)                            \
    CPLX2(c7r,c7i,Z1r,-Z1i, aR7,aI7,aR15,aI15)                            \
    ROT(c1r,c1i,e1x,e1y) ROT(c2r,c2i,e2x,e2y) ROT(c3r,c3i,e3x,e3y)        \
    ROT(c4r,c4i,e4x,e4y) ROT(c5r,c5i,e5x,e5y) ROT(c6r,c6i,e6x,e6y)        \
    ROT(c7r,c7i,e7x,e7y)                                                  \
    ROT(mAr,mAi,fAx,fAy) ROT(mBr,mBi,fBx,fBy)                             \
  }

  float vA[8], vB[8];
  LOADV(vA, 0)
  LOADV(vB, 1)

#pragma unroll 1
  for (int a = 0; a < 32; a += 2) {
    BODY(vA)
    if (a < 30) { LOADV(vA, a + 2) }
    BODY(vB)
    if (a < 30) { LOADV(vB, a + 3) }
  }
#undef BODY
#undef LOADV
#undef CPLX2
#undef ROT
#undef ACC2N

  // ---- stage 2 ----
  float* __restrict__ Mo = (isGt ? Gm : Pm) + (size_t)img * (MM * MM * 2);
  const int w     = t >> 6;          // wave id 0..7
  const int l     = t & 63;
  const int wv    = w & 3;           // residue k2 % 4 (wave-uniform)
  const int half2 = w >> 2;
  const int cl    = l >> 2;          // local k1 column 0..15
  const int k2    = 4 * (l & 3) + wv + 16 * half2;
  float rsn, rcs;
  __sincosf(-6.2831853e-3f * (float)k2 * 4.0869565f, &rsn, &rcs);  // dummy init (overwritten)
  __sincosf((float)(-2.0 * M_PI / 256.0) * (float)k2, &rsn, &rcs);
  const float rx = rcs, ry = rsn;    // rotator e^{-2pi i k2/256}
  float eacc = 0.f;

#define FLUSH(P)                                                          \
  if (half == (P)) {                                                      \
    float4* rowp = (float4*)&T2[col * PAD2];                              \
    rowp[0] = make_float4(aR0, aI0, aR1, aI1);                            \
    rowp[1] = make_float4(aR2, aI2, aR3, aI3);                            \
    rowp[2] = make_float4(aR4, aI4, aR5, aI5);                            \
    rowp[3] = make_float4(aR6, aI6, aR7, aI7);                            \
    rowp[4] = make_float4(aR8, aI8, aR9, aI9);                            \
    rowp[5] = make_float4(aR10, aI10, aR11, aI11);                        \
    rowp[6] = make_float4(aR12, aI12, aR13, aI13);                        \
    rowp[7] = make_float4(aR14, aI14, aR15, aI15);                        \
  }

#define PASS(P)                                                           \
  {                                                                       \
    float wr = 1.f, wi = 0.f, Xr = 0.f, Xi = 0.f;                         \
    _Pragma("unroll 4")                                                   \
    for (int n2 = 0; n2 < 64; ++n2) {                                     \
      float2 T0 = T2[(n2      ) * PAD2 + cl];                             \
      float2 T1 = T2[(n2 +  64) * PAD2 + cl];                             \
      float2 Tc = T2[(n2 + 128) * PAD2 + cl];                             \
      float2 T3 = T2[(n2 + 192) * PAD2 + cl];                             \
      float yr, yi;                                                       \
      if (wv == 0) {                                                      \
        yr = (T0.x + Tc.x) + (T1.x + T3.x);                               \
        yi = (T0.y + Tc.y) + (T1.y + T3.y);                               \
      } else if (wv == 2) {                                               \
        yr = (T0.x + Tc.x) - (T1.x + T3.x);                               \
        yi = (T0.y + Tc.y) - (T1.y + T3.y);                               \
      } else {                                                            \
        float s1r = T0.x - Tc.x, s1i = T0.y - Tc.y;                       \
        float s3r = T1.x - T3.x, s3i = T1.y - T3.y;                       \
        if (wv == 1) { yr = s1r + s3i; yi = s1i - s3r; }                  \
        else         { yr = s1r - s3i; yi = s1i + s3r; }                  \
      }                                                                   \
      Xr = fmaf(wr, yr, fmaf(-wi, yi, Xr));                               \
      Xi = fmaf(wr, yi, fmaf( wi, yr, Xi));                               \
      float nr_ = fmaf(wr, rx, -(wi * ry));                               \
      float ni_ = fmaf(wr, ry,  (wi * rx));                               \
      wr = nr_; wi = ni_;                                                 \
    }                                                                     \
    const int k1g  = 16 * (P) + cl;                                       \
    const int midx = k1g * MM + k2;                                       \
    ((float2*)Mo)[midx] = make_float2(Xr, Xi);                            \
    if (!isGt) {                                                          \
      float en = fmaf(Xr, Xr, Xi * Xi);                                   \
      out_energy[(size_t)img * (MM * MM) + midx] = en;                    \
      eacc += en;                                                         \
    }                                                                     \
  }

  FLUSH(0)
  __syncthreads();
  PASS(0)
  __syncthreads();     // all pass-0 reads done before overwrite
  FLUSH(1)
  __syncthreads();
  PASS(1)
#undef FLUSH
#undef PASS

  if (!isGt) {   // block-uniform branch
#pragma unroll
    for (int off = 32; off >= 1; off >>= 1) eacc += __shfl_down(eacc, off);
    if (l == 0) red[w] = eacc;
    __syncthreads();
    if (t == 0) {
      float s = 0.f;
#pragma unroll
      for (int j = 0; j < 8; ++j) s += red[j];
      tot[img] = s;
    }
  }
}

// ---------------------------------------------------------------------------
// Per-mode MLP + elementwise outputs. One thread per (img, mode).
__global__ __launch_bounds__(256) void mlp_kernel(
    const float* __restrict__ Pm, const float* __restrict__ Gm,
    const float* __restrict__ tot,
    const float* __restrict__ W1, const float* __restrict__ b1,
    const float* __restrict__ W2, const float* __restrict__ b2,
    const float* __restrict__ W3, const float* __restrict__ b3,
    float* __restrict__ out)
{
  int gid = blockIdx.x * 256 + threadIdx.x;   // 0 .. 524287
  int img = gid >> 10;

  float2 pm = *(const float2*)&Pm[2 * (size_t)gid];
  float2 gm = *(const float2*)&Gm[2 * (size_t)gid];

  float er = pm.x - gm.x, ei = pm.y - gm.y;
  float merr   = fmaf(er, er, ei * ei);
  float energy = fmaf(pm.x, pm.x, pm.y * pm.y);
  float frac   = energy / (tot[img] + EPSF);

  float h1[64];
#pragma unroll
  for (int j = 0; j < 64; ++j)
    h1[j] = fmaxf(fmaf(pm.x, W1[j], fmaf(pm.y, W1[64 + j], b1[j])), 0.f);

  float h2[32];
#pragma unroll
  for (int k = 0; k < 32; ++k) h2[k] = b2[k];
#pragma unroll
  for (int j = 0; j < 64; ++j) {
#pragma unroll
    for (int k = 0; k < 32; ++k)
      h2[k] = fmaf(h1[j], W2[j * 32 + k], h2[k]);
  }
  float z = b3[0];
#pragma unroll
  for (int k = 0; k < 32; ++k) z = fmaf(fmaxf(h2[k], 0.f), W3[k], z);

  float u = fmaxf(z, 0.f) + log1pf(expf(-fabsf(z)));

  out[O0 + gid] = energy;
  out[O1 + gid] = u;
  out[O2 + gid] = frac;
  out[O3 + gid] = frac * u;
  out[O6 + gid] = merr;
}

// ---------------------------------------------------------------------------
// Per-mode reductions over the 512-image axis: spectra + Pearson correlation.
__global__ __launch_bounds__(64) void corr_kernel(float* __restrict__ out)
{
  int mode = blockIdx.x;     // 0..1023
  int lane = threadIdx.x;    // 0..63

  double su = 0.0, se = 0.0, sen = 0.0, suu = 0.0, see = 0.0, sue = 0.0;
  for (int i = lane; i < NIMG; i += 64) {
    float u  = out[O1 + (size_t)i * 1024 + mode];
    float e  = out[O6 + (size_t)i * 1024 + mode];
    float en = out[O0 + (size_t)i * 1024 + mode];
    su  += (double)u;  se  += (double)e;  sen += (double)en;
    suu += (double)u * (double)u;
    see += (double)e * (double)e;
    sue += (double)u * (double)e;
  }
#pragma unroll
  for (int off = 32; off >= 1; off >>= 1) {
    su  += __shfl_down(su,  off);
    se  += __shfl_down(se,  off);
    sen += __shfl_down(sen, off);
    suu += __shfl_down(suu, off);
    see += __shfl_down(see, off);
    sue += __shfl_down(sue, off);
  }
  if (lane == 0) {
    const double N = (double)NIMG;
    double num = sue - su * se / N;
    double du  = suu - su * su / N;
    double de  = see - se * se / N;
    double den = sqrt(du * de);
    out[O4 + mode] = (float)(su / N);
    out[O5 + mode] = (float)(sen / N);
    out[O7 + mode] = (float)(num / (den + 1e-8));
  }
}

// ---------------------------------------------------------------------------
extern "C" void kernel_launch(void* const* d_in, const int* in_sizes, int n_in,
                              void* d_out, int out_size, void* d_ws, size_t ws_size,
                              hipStream_t stream)
{
  const float* pred = (const float*)d_in[0];
  const float* gt   = (const float*)d_in[2];
  const float* W1   = (const float*)d_in[3];
  const float* b1   = (const float*)d_in[4];
  const float* W2   = (const float*)d_in[5];
  const float* b2   = (const float*)d_in[6];
  const float* W3   = (const float*)d_in[7];
  const float* b3   = (const float*)d_in[8];

  float* out = (float*)d_out;
  float* ws  = (float*)d_ws;
  float* Pm  = ws + PM_OFF;
  float* Gm  = ws + GM_OFF;
  float* tot = ws + TOT_OFF;

  hipLaunchKernelGGL(dft_kernel, dim3(1024), dim3(512), 0, stream,
                     pred, gt, Pm, Gm, tot, out + O0);
  hipLaunchKernelGGL(mlp_kernel, dim3(2048), dim3(256), 0, stream,
                     Pm, Gm, tot, W1, b1, W2, b2, W3, b3, out);
  hipLaunchKernelGGL(corr_kernel, dim3(1024), dim3(64), 0, stream, out);
}

// Round 7
// 128.768 us; speedup vs baseline: 1.3065x; 1.3065x over previous
//
#include <hip/hip_runtime.h>
#include <math.h>

// Problem constants
#define NIMG 512          // B*C = 64*8
#define HH   256          // H
#define MM   32           // M (kept modes per axis)
#define EPSF 1e-8f
#define PAD2 18           // padded k1-stride (float2 units) for T2 (144B rows, 16B-aligned)

// d_out float offsets (outputs concatenated flat in reference return order)
#define O0 0u             // modal_energies        [512][32][32]
#define O1 524288u        // modal_uncertainties   [512][32][32]
#define O2 1048576u       // energy_fractions      [512][32][32]
#define O3 1572864u       // weighted_importance   [512][32][32]
#define O4 2097152u       // uncertainty_spectrum  [32][32]
#define O5 2098176u       // energy_spectrum       [32][32]
#define O6 2099200u       // modal_errors          [512][32][32]
#define O7 2623488u       // calibration_scores    [32][32]

// d_ws float offsets
#define PM_OFF  512                          // pred modes [512][32][32][2]
#define GM_OFF  (512 + NIMG*MM*MM*2)         // gt modes
#define TOT_OFF (512 + 2*NIMG*MM*MM*2)       // per-image total energy [512]

// ---------------------------------------------------------------------------
// Truncated 2D DFT: one block per (image, tensor). 256 threads (thread = n2).
// Stage 1 (DIT-8 over n1 = a + 32b, r3 structure - proven non-spilling):
//   per a, constant-twiddle 8-pt real DFT over b, then
//   X[8m+r] += W32^{am} * (W256^{ar} * Z[r]); twiddles from a 2KB LDS table
//   (wave-uniform broadcast reads). Input loads 2-deep prefetched (vA/vB).
//   All acc indices compile-time constants (incl. flush) -> SROA-safe.
// Stage 2 (two passes over k1-halves): radix-4 fold over n2 (64 iters,
//   unroll x4 -> 16 ds_read_b64 batched/body), residue k2%4 wave-uniform
//   and branchless; per-mode rotator by complex recurrence (sincosf init).
__global__ __launch_bounds__(256, 4) void dft_kernel(
    const float* __restrict__ pred, const float* __restrict__ gt,
    float* __restrict__ Pm, float* __restrict__ Gm,
    float* __restrict__ tot, float* __restrict__ out_energy)
{
  __shared__ __align__(16) float2 T2[256 * PAD2];   // 36864 B
  __shared__ float2 tws[256];                       // 2 KB twiddle table
  __shared__ float red[4];

  const int t    = threadIdx.x;
  const int img  = blockIdx.x & (NIMG - 1);
  const int isGt = blockIdx.x >> 9;
  const float* __restrict__ x =
      (isGt ? gt : pred) + (size_t)img * (HH * HH) + t;

  // build twiddle table: tws[i] = (cos, sin)(2*pi*i/256)
  {
    float sn, cs;
    __sincosf((float)(2.0 * M_PI / 256.0) * (float)t, &sn, &cs);
    tws[t] = make_float2(cs, sn);
  }
  __syncthreads();

  // ---- stage 1: DIT-8 over n1 ----
  float accR[32], accI[32];
#pragma unroll
  for (int k = 0; k < 32; ++k) { accR[k] = 0.f; accI[k] = 0.f; }

#define ACC4(r, Yr, Yi)                                                   \
    accR[(r)]    += (Yr);  accI[(r)]    += (Yi);                          \
    accR[8+(r)]  = fmaf(m1r,(Yr), fmaf( m1s,(Yi), accR[8+(r)]));          \
    accI[8+(r)]  = fmaf(m1r,(Yi), fmaf(-m1s,(Yr), accI[8+(r)]));          \
    accR[16+(r)] = fmaf(m2r,(Yr), fmaf( m2s,(Yi), accR[16+(r)]));         \
    accI[16+(r)] = fmaf(m2r,(Yi), fmaf(-m2s,(Yr), accI[16+(r)]));         \
    accR[24+(r)] = fmaf(m3r,(Yr), fmaf( m3s,(Yi), accR[24+(r)]));         \
    accI[24+(r)] = fmaf(m3r,(Yi), fmaf(-m3s,(Yr), accI[24+(r)]));

#define CPLX_R(r, aa, Zr, Zi)                                             \
    {                                                                     \
      float2 tt = tws[((r) * (aa)) & 255];                                \
      float Yr = fmaf(tt.x, (Zr),  tt.y * (Zi));                          \
      float Yi = fmaf(tt.x, (Zi), -(tt.y * (Zr)));                        \
      ACC4(r, Yr, Yi)                                                     \
    }

#define LOADV(V, aa)                                                      \
    V[0] = x[(aa)*256];         V[1] = x[(aa)*256 +  8192];               \
    V[2] = x[(aa)*256 + 16384]; V[3] = x[(aa)*256 + 24576];               \
    V[4] = x[(aa)*256 + 32768]; V[5] = x[(aa)*256 + 40960];               \
    V[6] = x[(aa)*256 + 49152]; V[7] = x[(aa)*256 + 57344];

#define BODY(V, aa)                                                       \
  {                                                                       \
    float v0=V[0],v1=V[1],v2=V[2],v3=V[3],v4=V[4],v5=V[5],v6=V[6],v7=V[7];\
    float w0=v0+v4, w1=v1+v5, w2=v2+v6, w3=v3+v7;                         \
    float d0=v0-v4, d1=v1-v5, d2=v2-v6, d3=v3-v7;                         \
    float A0=w0+w2, A1=w0-w2, A2=w1+w3, A3=w1-w3;                         \
    float Z0=A0+A2, Z4=A0-A2;                                             \
    float Z2r=A1, Z2i=-A3;                                                \
    const float SQ = 0.70710678f;                                         \
    float pp=SQ*(d1-d3), qq2=SQ*(d1+d3);                                  \
    float Z1r=d0+pp, Z1i=-(d2+qq2);                                       \
    float Z3r=d0-pp, Z3i=d2-qq2;                                          \
    float2 tm1 = tws[( 8*(aa)) & 255];                                    \
    float2 tm2 = tws[(16*(aa)) & 255];                                    \
    float2 tm3 = tws[(24*(aa)) & 255];                                    \
    float m1r = tm1.x, m1s = tm1.y;                                       \
    float m2r = tm2.x, m2s = tm2.y;                                       \
    float m3r = tm3.x, m3s = tm3.y;                                       \
    /* r=0: Y = (Z0, 0) */                                                \
    accR[0] += Z0;                                                        \
    accR[8]  = fmaf(m1r,Z0,accR[8]);  accI[8]  = fmaf(-m1s,Z0,accI[8]);   \
    accR[16] = fmaf(m2r,Z0,accR[16]); accI[16] = fmaf(-m2s,Z0,accI[16]);  \
    accR[24] = fmaf(m3r,Z0,accR[24]); accI[24] = fmaf(-m3s,Z0,accI[24]);  \
    /* r=4: Y = W256^{4a} * Z4 (Z4 real) */                               \
    { float2 tt = tws[(4*(aa)) & 255];                                    \
      float Yr = tt.x * Z4, Yi = -(tt.y * Z4);                            \
      ACC4(4, Yr, Yi) }                                                   \
    CPLX_R(1, (aa), Z1r,  Z1i)                                            \
    CPLX_R(2, (aa), Z2r,  Z2i)                                            \
    CPLX_R(3, (aa), Z3r,  Z3i)                                            \
    CPLX_R(5, (aa), Z3r, -Z3i)                                            \
    CPLX_R(6, (aa), Z2r, -Z2i)                                            \
    CPLX_R(7, (aa), Z1r, -Z1i)                                            \
  }

  float vA[8], vB[8];
  LOADV(vA, 0)
  LOADV(vB, 1)

#pragma unroll 1
  for (int a = 0; a < 32; a += 2) {
    BODY(vA, a)
    if (a < 30) { LOADV(vA, a + 2) }
    BODY(vB, a + 1)
    if (a < 30) { LOADV(vB, a + 3) }
  }
#undef BODY
#undef LOADV
#undef CPLX_R
#undef ACC4

  // ---- stage 2: two passes over k1-halves, radix-4 fold over n2 ----
  float* __restrict__ Mo = (isGt ? Gm : Pm) + (size_t)img * (MM * MM * 2);
  const int wv  = t >> 6;        // wave id = residue k2 % 4 (wave-uniform)
  const int l   = t & 63;
  const int k1l = l >> 2;        // 0..15
  const int qq  = l & 3;
  const int k2A = 4 * qq + wv;
  const int k2B = k2A + 16;
  float sA, cA, sB, cB;
  __sincosf((float)(-2.0 * M_PI / 256.0) * (float)k2A, &sA, &cA);
  __sincosf((float)(-2.0 * M_PI / 256.0) * (float)k2B, &sB, &cB);
  const float se = (wv & 1) ? -1.f : 1.f;     // fold sign for T_c/T_3
  const float cc = (wv < 2) ? 1.f : -1.f;     // second-term sign
  const bool  ev = (wv & 1) == 0;
  float eacc = 0.f;

#define FLUSH(base)                                                       \
  {                                                                       \
    float4* rowp = (float4*)&T2[t * PAD2];                                \
    rowp[0] = make_float4(accR[(base)+ 0],accI[(base)+ 0],accR[(base)+ 1],accI[(base)+ 1]); \
    rowp[1] = make_float4(accR[(base)+ 2],accI[(base)+ 2],accR[(base)+ 3],accI[(base)+ 3]); \
    rowp[2] = make_float4(accR[(base)+ 4],accI[(base)+ 4],accR[(base)+ 5],accI[(base)+ 5]); \
    rowp[3] = make_float4(accR[(base)+ 6],accI[(base)+ 6],accR[(base)+ 7],accI[(base)+ 7]); \
    rowp[4] = make_float4(accR[(base)+ 8],accI[(base)+ 8],accR[(base)+ 9],accI[(base)+ 9]); \
    rowp[5] = make_float4(accR[(base)+10],accI[(base)+10],accR[(base)+11],accI[(base)+11]); \
    rowp[6] = make_float4(accR[(base)+12],accI[(base)+12],accR[(base)+13],accI[(base)+13]); \
    rowp[7] = make_float4(accR[(base)+14],accI[(base)+14],accR[(base)+15],accI[(base)+15]); \
  }

#define PASS(P)                                                           \
  {                                                                       \
    float wAr = 1.f, wAi = 0.f, wBr = 1.f, wBi = 0.f;                     \
    float XAr = 0.f, XAi = 0.f, XBr = 0.f, XBi = 0.f;                     \
    _Pragma("unroll 4")                                                   \
    for (int n2 = 0; n2 < 64; ++n2) {                                     \
      float2 T0 = T2[(n2      ) * PAD2 + k1l];                            \
      float2 T1 = T2[(n2 +  64) * PAD2 + k1l];                            \
      float2 Tc = T2[(n2 + 128) * PAD2 + k1l];                            \
      float2 T3 = T2[(n2 + 192) * PAD2 + k1l];                            \
      float sr = fmaf(se, Tc.x, T0.x), si = fmaf(se, Tc.y, T0.y);         \
      float tr = fmaf(se, T3.x, T1.x), ti = fmaf(se, T3.y, T1.y);         \
      float ur = ev ? tr : ti;                                            \
      float ui = ev ? ti : -tr;                                           \
      float yr = fmaf(cc, ur, sr), yi = fmaf(cc, ui, si);                 \
      XAr = fmaf(wAr, yr, fmaf(-wAi, yi, XAr));                           \
      XAi = fmaf(wAr, yi, fmaf( wAi, yr, XAi));                           \
      XBr = fmaf(wBr, yr, fmaf(-wBi, yi, XBr));                           \
      XBi = fmaf(wBr, yi, fmaf( wBi, yr, XBi));                           \
      float nAr = fmaf(wAr, cA, -(wAi * sA));                             \
      float nAi = fmaf(wAr, sA,  (wAi * cA));                             \
      float nBr = fmaf(wBr, cB, -(wBi * sB));                             \
      float nBi = fmaf(wBr, sB,  (wBi * cB));                             \
      wAr = nAr; wAi = nAi; wBr = nBr; wBi = nBi;                         \
    }                                                                     \
    const int k1g = k1l + 16 * (P);                                       \
    const int mA  = k1g * MM + k2A;                                       \
    const int mB  = k1g * MM + k2B;                                       \
    ((float2*)Mo)[mA] = make_float2(XAr, XAi);                            \
    ((float2*)Mo)[mB] = make_float2(XBr, XBi);                            \
    if (!isGt) {                                                          \
      float eA = fmaf(XAr, XAr, XAi * XAi);                               \
      float eB = fmaf(XBr, XBr, XBi * XBi);                               \
      out_energy[(size_t)img * (MM * MM) + mA] = eA;                      \
      out_energy[(size_t)img * (MM * MM) + mB] = eB;                      \
      eacc += eA + eB;                                                    \
    }                                                                     \
  }

  FLUSH(0)
  __syncthreads();
  PASS(0)
  __syncthreads();     // all pass-0 reads done before overwrite
  FLUSH(16)
  __syncthreads();
  PASS(1)
#undef FLUSH
#undef PASS

  if (!isGt) {   // block-uniform branch
#pragma unroll
    for (int off = 32; off >= 1; off >>= 1) eacc += __shfl_down(eacc, off);
    if ((t & 63) == 0) red[t >> 6] = eacc;
    __syncthreads();
    if (t == 0) tot[img] = (red[0] + red[1]) + (red[2] + red[3]);
  }
}

// ---------------------------------------------------------------------------
// Per-mode MLP + elementwise outputs. One thread per (img, mode).
__global__ __launch_bounds__(256) void mlp_kernel(
    const float* __restrict__ Pm, const float* __restrict__ Gm,
    const float* __restrict__ tot,
    const float* __restrict__ W1, const float* __restrict__ b1,
    const float* __restrict__ W2, const float* __restrict__ b2,
    const float* __restrict__ W3, const float* __restrict__ b3,
    float* __restrict__ out)
{
  int gid = blockIdx.x * 256 + threadIdx.x;   // 0 .. 524287
  int img = gid >> 10;

  float2 pm = *(const float2*)&Pm[2 * (size_t)gid];
  float2 gm = *(const float2*)&Gm[2 * (size_t)gid];

  float er = pm.x - gm.x, ei = pm.y - gm.y;
  float merr   = fmaf(er, er, ei * ei);
  float energy = fmaf(pm.x, pm.x, pm.y * pm.y);
  float frac   = energy / (tot[img] + EPSF);

  float h1[64];
#pragma unroll
  for (int j = 0; j < 64; ++j)
    h1[j] = fmaxf(fmaf(pm.x, W1[j], fmaf(pm.y, W1[64 + j], b1[j])), 0.f);

  float h2[32];
#pragma unroll
  for (int k = 0; k < 32; ++k) h2[k] = b2[k];
#pragma unroll
  for (int j = 0; j < 64; ++j) {
#pragma unroll
    for (int k = 0; k < 32; ++k)
      h2[k] = fmaf(h1[j], W2[j * 32 + k], h2[k]);
  }
  float z = b3[0];
#pragma unroll
  for (int k = 0; k < 32; ++k) z = fmaf(fmaxf(h2[k], 0.f), W3[k], z);

  float u = fmaxf(z, 0.f) + log1pf(expf(-fabsf(z)));

  out[O0 + gid] = energy;
  out[O1 + gid] = u;
  out[O2 + gid] = frac;
  out[O3 + gid] = frac * u;
  out[O6 + gid] = merr;
}

// ---------------------------------------------------------------------------
// Per-mode reductions over the 512-image axis: spectra + Pearson correlation.
__global__ __launch_bounds__(64) void corr_kernel(float* __restrict__ out)
{
  int mode = blockIdx.x;     // 0..1023
  int lane = threadIdx.x;    // 0..63

  double su = 0.0, se = 0.0, sen = 0.0, suu = 0.0, see = 0.0, sue = 0.0;
  for (int i = lane; i < NIMG; i += 64) {
    float u  = out[O1 + (size_t)i * 1024 + mode];
    float e  = out[O6 + (size_t)i * 1024 + mode];
    float en = out[O0 + (size_t)i * 1024 + mode];
    su  += (double)u;  se  += (double)e;  sen += (double)en;
    suu += (double)u * (double)u;
    see += (double)e * (double)e;
    sue += (double)u * (double)e;
  }
#pragma unroll
  for (int off = 32; off >= 1; off >>= 1) {
    su  += __shfl_down(su,  off);
    se  += __shfl_down(se,  off);
    sen += __shfl_down(sen, off);
    suu += __shfl_down(suu, off);
    see += __shfl_down(see, off);
    sue += __shfl_down(sue, off);
  }
  if (lane == 0) {
    const double N = (double)NIMG;
    double num = sue - su * se / N;
    double du  = suu - su * su / N;
    double de  = see - se * se / N;
    double den = sqrt(du * de);
    out[O4 + mode] = (float)(su / N);
    out[O5 + mode] = (float)(sen / N);
    out[O7 + mode] = (float)(num / (den + 1e-8));
  }
}

// ---------------------------------------------------------------------------
extern "C" void kernel_launch(void* const* d_in, const int* in_sizes, int n_in,
                              void* d_out, int out_size, void* d_ws, size_t ws_size,
                              hipStream_t stream)
{
  const float* pred = (const float*)d_in[0];
  const float* gt   = (const float*)d_in[2];
  const float* W1   = (const float*)d_in[3];
  const float* b1   = (const float*)d_in[4];
  const float* W2   = (const float*)d_in[5];
  const float* b2   = (const float*)d_in[6];
  const float* W3   = (const float*)d_in[7];
  const float* b3   = (const float*)d_in[8];

  float* out = (float*)d_out;
  float* ws  = (float*)d_ws;
  float* Pm  = ws + PM_OFF;
  float* Gm  = ws + GM_OFF;
  float* tot = ws + TOT_OFF;

  hipLaunchKernelGGL(dft_kernel, dim3(1024), dim3(256), 0, stream,
                     pred, gt, Pm, Gm, tot, out + O0);
  hipLaunchKernelGGL(mlp_kernel, dim3(2048), dim3(256), 0, stream,
                     Pm, Gm, tot, W1, b1, W2, b2, W3, b3, out);
  hipLaunchKernelGGL(corr_kernel, dim3(1024), dim3(64), 0, stream, out);
}